// Round 1
// baseline (803.727 us; speedup 1.0000x reference)
//
#include <hip/hip_runtime.h>
#include <hip/hip_bf16.h>
#include <math.h>

// Problem constants (B,N,L,DM) = (2,2,1024,512), EXPAND=2, D_STATE=16, D_CONV=4
// D_INNER = 1024, DT_RANK = 32, BN_ = B*N = 4, M = BN_*L = 4096
#define L_SEQ   1024
#define DM_     512
#define D_INNER 1024
#define D_STATE 16
#define DT_RANK 32
#define BN_     4
#define M_ROWS  4096

// ---------------- f32 tiled GEMM: C[M,N] = A[M,K] @ W[N,K]^T ----------------
#define BM 64
#define BNT 64
#define BK 16

__global__ __launch_bounds__(256) void gemm_f32(const float* __restrict__ A,
                                                const float* __restrict__ W,
                                                float* __restrict__ C,
                                                int Mdim, int Ndim, int Kdim) {
  __shared__ float As[BK][BM];
  __shared__ float Bs[BK][BNT];
  const int tid = threadIdx.x;
  const int bm = blockIdx.y * BM;
  const int bn = blockIdx.x * BNT;
  const int tx = tid & 15;       // 0..15 -> 4 cols each
  const int ty = tid >> 4;       // 0..15 -> 4 rows each
  const int lr = tid >> 2;       // 0..63 row within tile for loads
  const int lk = (tid & 3) * 4;  // k offset 0,4,8,12

  float acc[4][4] = {};

  for (int k0 = 0; k0 < Kdim; k0 += BK) {
    float4 av = *(const float4*)&A[(size_t)(bm + lr) * Kdim + k0 + lk];
    float4 bv = *(const float4*)&W[(size_t)(bn + lr) * Kdim + k0 + lk];
    __syncthreads();
    As[lk + 0][lr] = av.x; As[lk + 1][lr] = av.y;
    As[lk + 2][lr] = av.z; As[lk + 3][lr] = av.w;
    Bs[lk + 0][lr] = bv.x; Bs[lk + 1][lr] = bv.y;
    Bs[lk + 2][lr] = bv.z; Bs[lk + 3][lr] = bv.w;
    __syncthreads();
#pragma unroll
    for (int k = 0; k < BK; ++k) {
      float ar[4], br[4];
      *(float4*)ar = *(const float4*)&As[k][ty * 4];
      *(float4*)br = *(const float4*)&Bs[k][tx * 4];
#pragma unroll
      for (int i = 0; i < 4; ++i)
#pragma unroll
        for (int j = 0; j < 4; ++j)
          acc[i][j] = fmaf(ar[i], br[j], acc[i][j]);
    }
  }
#pragma unroll
  for (int i = 0; i < 4; ++i) {
    int row = bm + ty * 4 + i;
    float4 v = make_float4(acc[i][0], acc[i][1], acc[i][2], acc[i][3]);
    *(float4*)&C[(size_t)row * Ndim + bn + tx * 4] = v;
  }
}

// ---------------- depthwise causal conv (d_conv=4) + SiLU ----------------
// xr layout: [M_ROWS][2048]; cols 0..1023 = x_in, 1024..2047 = res
__global__ __launch_bounds__(256) void conv_silu_kernel(const float* __restrict__ xr,
                                                        const float* __restrict__ cw,
                                                        const float* __restrict__ cb,
                                                        float* __restrict__ u) {
  int idx = blockIdx.x * 256 + threadIdx.x;  // over M_ROWS * D_INNER
  int d = idx & (D_INNER - 1);
  int m = idx >> 10;
  int l = m & (L_SEQ - 1);
  int bn = m >> 10;
  int ch = (bn & 1) * D_INNER + d;  // n = bn % N, N=2
  float acc = cb[ch];
  const float* base = xr + (size_t)(bn << 10) * 2048 + d;
#pragma unroll
  for (int k = 0; k < 4; ++k) {
    int ll = l - 3 + k;
    if (ll >= 0) acc = fmaf(cw[ch * 4 + k], base[(size_t)ll * 2048], acc);
  }
  float sig = 1.f / (1.f + __expf(-acc));
  u[idx] = acc * sig;
}

// ---------------- x-proj: proj[M,64] = u[M,1024] @ Wx[64,1024]^T ----------------
__global__ __launch_bounds__(256) void proj_kernel(const float* __restrict__ u,
                                                   const float* __restrict__ Wx,
                                                   float* __restrict__ proj) {
  int wave = threadIdx.x >> 6;
  int lane = threadIdx.x & 63;
  int m = blockIdx.x * 4 + wave;
  const float* up = u + (size_t)m * D_INNER;
  const float* wp = Wx + (size_t)lane * D_INNER;
  float acc = 0.f;
#pragma unroll 4
  for (int k = 0; k < D_INNER; k += 4) {
    float4 uu = *(const float4*)(up + k);
    float4 ww = *(const float4*)(wp + k);
    acc = fmaf(uu.x, ww.x, acc);
    acc = fmaf(uu.y, ww.y, acc);
    acc = fmaf(uu.z, ww.z, acc);
    acc = fmaf(uu.w, ww.w, acc);
  }
  proj[m * 64 + lane] = acc;
}

// ---------------- dt-proj + softplus: dt[M,1024] ----------------
__global__ __launch_bounds__(256) void dt_kernel(const float* __restrict__ proj,
                                                 const float* __restrict__ Wdt,
                                                 const float* __restrict__ bdt,
                                                 float* __restrict__ dt) {
  __shared__ float row[DT_RANK];
  int m = blockIdx.y;
  int d = blockIdx.x * 256 + threadIdx.x;
  if (threadIdx.x < DT_RANK) row[threadIdx.x] = proj[m * 64 + threadIdx.x];
  __syncthreads();
  float acc = bdt[d];
  const float* w = Wdt + (size_t)d * DT_RANK;
#pragma unroll
  for (int r = 0; r < DT_RANK; r += 4) {
    float4 ww = *(const float4*)(w + r);
    acc = fmaf(row[r + 0], ww.x, acc);
    acc = fmaf(row[r + 1], ww.y, acc);
    acc = fmaf(row[r + 2], ww.z, acc);
    acc = fmaf(row[r + 3], ww.w, acc);
  }
  // stable softplus
  float sp = fmaxf(acc, 0.f) + log1pf(__expf(-fabsf(acc)));
  dt[(size_t)m * D_INNER + d] = sp;
}

// ---------------- fused selective scan + gate ----------------
// lane layout: lane = c*16 + s ; wave handles 4 channels (d values)
// h_{l} = exp(dt*A)*h_{l-1} + dt*B*u ; y = sum_s h*C ; g = (y + u*Dp)*silu(res)
__global__ __launch_bounds__(256) void scan_kernel(const float* __restrict__ dt,
                                                   const float* __restrict__ u,
                                                   const float* __restrict__ proj,
                                                   const float* __restrict__ xr,
                                                   const float* __restrict__ A_log,
                                                   const float* __restrict__ Dp,
                                                   float* __restrict__ g) {
  int wave = threadIdx.x >> 6;
  int lane = threadIdx.x & 63;
  int s = lane & 15;
  int c = lane >> 4;
  int ch = blockIdx.x * 16 + wave * 4 + c;  // 0..4095
  int bn = ch >> 10;
  int d = ch & (D_INNER - 1);

  float A = -__expf(A_log[d * D_STATE + s]);
  float Dpd = Dp[d];
  float h = 0.f;

  int m0 = bn << 10;
  // prefetch l = 0
  float dtv = dt[(size_t)m0 * D_INNER + d];
  float uv = u[(size_t)m0 * D_INNER + d];
  float Bv = proj[m0 * 64 + 32 + s];
  float Cv = proj[m0 * 64 + 48 + s];
  float rv = xr[(size_t)m0 * 2048 + D_INNER + d];

  for (int l = 0; l < L_SEQ; ++l) {
    float dtc = dtv, uc = uv, Bc = Bv, Cc = Cv, rc = rv;
    if (l < L_SEQ - 1) {
      int m2 = m0 + l + 1;
      dtv = dt[(size_t)m2 * D_INNER + d];
      uv = u[(size_t)m2 * D_INNER + d];
      Bv = proj[m2 * 64 + 32 + s];
      Cv = proj[m2 * 64 + 48 + s];
      rv = xr[(size_t)m2 * 2048 + D_INNER + d];
    }
    float a = __expf(dtc * A);
    h = fmaf(a, h, dtc * Bc * uc);
    float p = h * Cc;
    p += __shfl_xor(p, 1);
    p += __shfl_xor(p, 2);
    p += __shfl_xor(p, 4);
    p += __shfl_xor(p, 8);
    if (s == 0) {
      float yv = p + uc * Dpd;
      float sg = 1.f / (1.f + __expf(-rc));
      g[(size_t)(m0 + l) * D_INNER + d] = yv * (rc * sg);
    }
  }
}

extern "C" void kernel_launch(void* const* d_in, const int* in_sizes, int n_in,
                              void* d_out, int out_size, void* d_ws, size_t ws_size,
                              hipStream_t stream) {
  const float* x      = (const float*)d_in[0];   // (2,2,1024,512)
  const float* W_in   = (const float*)d_in[1];   // (2048, 512)
  const float* conv_w = (const float*)d_in[2];   // (2048, 4)
  const float* conv_b = (const float*)d_in[3];   // (2048,)
  const float* W_x    = (const float*)d_in[4];   // (64, 1024)
  const float* W_dt   = (const float*)d_in[5];   // (1024, 32)
  const float* b_dt   = (const float*)d_in[6];   // (1024,)
  const float* A_log  = (const float*)d_in[7];   // (1024, 16)
  const float* Dp     = (const float*)d_in[8];   // (1024,)
  const float* W_out  = (const float*)d_in[9];   // (512, 1024)
  float* out = (float*)d_out;                    // (2,2,1024,512)

  float* ws = (float*)d_ws;
  float* xr   = ws;                          // [4096][2048]  (x_in | res)
  float* u    = xr + (size_t)M_ROWS * 2048;  // [4096][1024]
  float* proj = u + (size_t)M_ROWS * 1024;   // [4096][64]
  float* dt   = proj + (size_t)M_ROWS * 64;  // [4096][1024]
  float* g    = dt + (size_t)M_ROWS * 1024;  // [4096][1024]

  // 1) in-proj GEMM: xr = x @ W_in^T   (M=4096, N=2048, K=512)
  {
    dim3 grid(2048 / BNT, M_ROWS / BM);
    gemm_f32<<<grid, 256, 0, stream>>>(x, W_in, xr, M_ROWS, 2048, DM_);
  }
  // 2) depthwise conv + SiLU -> u
  conv_silu_kernel<<<(M_ROWS * D_INNER) / 256, 256, 0, stream>>>(xr, conv_w, conv_b, u);
  // 3) x-proj -> proj (dt_raw | B | C)
  proj_kernel<<<M_ROWS / 4, 256, 0, stream>>>(u, W_x, proj);
  // 4) dt-proj + softplus -> dt
  {
    dim3 grid(D_INNER / 256, M_ROWS);
    dt_kernel<<<grid, 256, 0, stream>>>(proj, W_dt, b_dt, dt);
  }
  // 5) fused selective scan + gating -> g
  scan_kernel<<<M_ROWS / 16, 256, 0, stream>>>(dt, u, proj, xr, A_log, Dp, g);
  // 6) out-proj GEMM: out = g @ W_out^T (M=4096, N=512, K=1024)
  {
    dim3 grid(512 / BNT, M_ROWS / BM);
    gemm_f32<<<grid, 256, 0, stream>>>(g, W_out, out, M_ROWS, 512, D_INNER);
  }
}

// Round 2
// 561.778 us; speedup vs baseline: 1.4307x; 1.4307x over previous
//
#include <hip/hip_runtime.h>
#include <hip/hip_bf16.h>
#include <math.h>

// Problem constants (B,N,L,DM) = (2,2,1024,512), EXPAND=2, D_STATE=16, D_CONV=4
// D_INNER = 1024, DT_RANK = 32, BN_ = B*N = 4, M = BN_*L = 4096
#define L_SEQ   1024
#define DM_     512
#define D_INNER 1024
#define D_STATE 16
#define DT_RANK 32
#define BN_     4
#define M_ROWS  4096

// chunked scan
#define CH   16            // chunks per sequence
#define LC   (L_SEQ / CH)  // 64 steps per chunk
#define NCHS (M_ROWS * D_STATE * 4 / 4)  // 4096 channels * 16 states = 65536

// ---------------- f32 tiled GEMM: C[M,N] = A[M,K] @ W[N,K]^T ----------------
#define BM 64
#define BNT 64
#define BK 16

__global__ __launch_bounds__(256) void gemm_f32(const float* __restrict__ A,
                                                const float* __restrict__ W,
                                                float* __restrict__ C,
                                                int Mdim, int Ndim, int Kdim) {
  __shared__ float As[BK][BM];
  __shared__ float Bs[BK][BNT];
  const int tid = threadIdx.x;
  const int bm = blockIdx.y * BM;
  const int bn = blockIdx.x * BNT;
  const int tx = tid & 15;       // 0..15 -> 4 cols each
  const int ty = tid >> 4;       // 0..15 -> 4 rows each
  const int lr = tid >> 2;       // 0..63 row within tile for loads
  const int lk = (tid & 3) * 4;  // k offset 0,4,8,12

  float acc[4][4] = {};

  for (int k0 = 0; k0 < Kdim; k0 += BK) {
    float4 av = *(const float4*)&A[(size_t)(bm + lr) * Kdim + k0 + lk];
    float4 bv = *(const float4*)&W[(size_t)(bn + lr) * Kdim + k0 + lk];
    __syncthreads();
    As[lk + 0][lr] = av.x; As[lk + 1][lr] = av.y;
    As[lk + 2][lr] = av.z; As[lk + 3][lr] = av.w;
    Bs[lk + 0][lr] = bv.x; Bs[lk + 1][lr] = bv.y;
    Bs[lk + 2][lr] = bv.z; Bs[lk + 3][lr] = bv.w;
    __syncthreads();
#pragma unroll
    for (int k = 0; k < BK; ++k) {
      float ar[4], br[4];
      *(float4*)ar = *(const float4*)&As[k][ty * 4];
      *(float4*)br = *(const float4*)&Bs[k][tx * 4];
#pragma unroll
      for (int i = 0; i < 4; ++i)
#pragma unroll
        for (int j = 0; j < 4; ++j)
          acc[i][j] = fmaf(ar[i], br[j], acc[i][j]);
    }
  }
#pragma unroll
  for (int i = 0; i < 4; ++i) {
    int row = bm + ty * 4 + i;
    float4 v = make_float4(acc[i][0], acc[i][1], acc[i][2], acc[i][3]);
    *(float4*)&C[(size_t)row * Ndim + bn + tx * 4] = v;
  }
}

// ---------------- depthwise causal conv (d_conv=4) + SiLU ----------------
// xr layout: [M_ROWS][2048]; cols 0..1023 = x_in, 1024..2047 = res
__global__ __launch_bounds__(256) void conv_silu_kernel(const float* __restrict__ xr,
                                                        const float* __restrict__ cw,
                                                        const float* __restrict__ cb,
                                                        float* __restrict__ u) {
  int idx = blockIdx.x * 256 + threadIdx.x;  // over M_ROWS * D_INNER
  int d = idx & (D_INNER - 1);
  int m = idx >> 10;
  int l = m & (L_SEQ - 1);
  int bn = m >> 10;
  int ch = (bn & 1) * D_INNER + d;  // n = bn % N, N=2
  float acc = cb[ch];
  const float* base = xr + (size_t)(bn << 10) * 2048 + d;
#pragma unroll
  for (int k = 0; k < 4; ++k) {
    int ll = l - 3 + k;
    if (ll >= 0) acc = fmaf(cw[ch * 4 + k], base[(size_t)ll * 2048], acc);
  }
  float sig = 1.f / (1.f + __expf(-acc));
  u[idx] = acc * sig;
}

// ---------------- x-proj: proj[M,64] = u[M,1024] @ Wx[64,1024]^T ----------------
__global__ __launch_bounds__(256) void proj_kernel(const float* __restrict__ u,
                                                   const float* __restrict__ Wx,
                                                   float* __restrict__ proj) {
  int wave = threadIdx.x >> 6;
  int lane = threadIdx.x & 63;
  int m = blockIdx.x * 4 + wave;
  const float* up = u + (size_t)m * D_INNER;
  const float* wp = Wx + (size_t)lane * D_INNER;
  float acc = 0.f;
#pragma unroll 4
  for (int k = 0; k < D_INNER; k += 4) {
    float4 uu = *(const float4*)(up + k);
    float4 ww = *(const float4*)(wp + k);
    acc = fmaf(uu.x, ww.x, acc);
    acc = fmaf(uu.y, ww.y, acc);
    acc = fmaf(uu.z, ww.z, acc);
    acc = fmaf(uu.w, ww.w, acc);
  }
  proj[m * 64 + lane] = acc;
}

// ---------------- dt-proj + softplus: dt[M,1024] ----------------
__global__ __launch_bounds__(256) void dt_kernel(const float* __restrict__ proj,
                                                 const float* __restrict__ Wdt,
                                                 const float* __restrict__ bdt,
                                                 float* __restrict__ dt) {
  __shared__ float row[DT_RANK];
  int m = blockIdx.y;
  int d = blockIdx.x * 256 + threadIdx.x;
  if (threadIdx.x < DT_RANK) row[threadIdx.x] = proj[m * 64 + threadIdx.x];
  __syncthreads();
  float acc = bdt[d];
  const float* w = Wdt + (size_t)d * DT_RANK;
#pragma unroll
  for (int r = 0; r < DT_RANK; r += 4) {
    float4 ww = *(const float4*)(w + r);
    acc = fmaf(row[r + 0], ww.x, acc);
    acc = fmaf(row[r + 1], ww.y, acc);
    acc = fmaf(row[r + 2], ww.z, acc);
    acc = fmaf(row[r + 3], ww.w, acc);
  }
  // stable softplus
  float sp = fmaxf(acc, 0.f) + log1pf(__expf(-fabsf(acc)));
  dt[(size_t)m * D_INNER + d] = sp;
}

// ---------------- chunked selective scan ----------------
// lane layout: lane = c*16 + s ; wave handles 4 channels; block = 16 channels
// blockIdx.x: low 8 bits = channel-group (256 groups of 16), high bits = chunk

// Pass A: per (ch, s, chunk) compute transfer P = prod(a), S = local scan from 0
__global__ __launch_bounds__(256) void scan_passA(const float* __restrict__ dt,
                                                  const float* __restrict__ u,
                                                  const float* __restrict__ proj,
                                                  const float* __restrict__ A_log,
                                                  float* __restrict__ Pbuf,
                                                  float* __restrict__ Sbuf) {
  int wave = threadIdx.x >> 6;
  int lane = threadIdx.x & 63;
  int s = lane & 15;
  int c = lane >> 4;
  int chunk = blockIdx.x >> 8;
  int chg = blockIdx.x & 255;
  int ch = chg * 16 + wave * 4 + c;  // 0..4095
  int bn = ch >> 10;
  int d = ch & (D_INNER - 1);

  float A = -__expf(A_log[d * D_STATE + s]);
  int m0 = (bn << 10) + chunk * LC;

  float P = 1.f, S = 0.f;
  for (int l = 0; l < LC; ++l) {
    int m = m0 + l;
    float dtv = dt[(size_t)m * D_INNER + d];
    float uv = u[(size_t)m * D_INNER + d];
    float Bv = proj[m * 64 + 32 + s];
    float a = __expf(dtv * A);
    float b = dtv * Bv * uv;
    P *= a;
    S = fmaf(a, S, b);
  }
  int gid = ch * D_STATE + s;
  Pbuf[chunk * NCHS + gid] = P;
  Sbuf[chunk * NCHS + gid] = S;
}

// Pass B: serial prefix over chunks -> h_in per chunk
__global__ __launch_bounds__(256) void scan_passB(const float* __restrict__ Pbuf,
                                                  const float* __restrict__ Sbuf,
                                                  float* __restrict__ Hin) {
  int gid = blockIdx.x * 256 + threadIdx.x;  // 0..NCHS-1
  float h = 0.f;
#pragma unroll
  for (int cidx = 0; cidx < CH; ++cidx) {
    Hin[cidx * NCHS + gid] = h;
    h = fmaf(Pbuf[cidx * NCHS + gid], h, Sbuf[cidx * NCHS + gid]);
  }
}

// Pass C: recompute chunk scan from h_in, reduce over s, gate, write g
__global__ __launch_bounds__(256) void scan_passC(const float* __restrict__ dt,
                                                  const float* __restrict__ u,
                                                  const float* __restrict__ proj,
                                                  const float* __restrict__ xr,
                                                  const float* __restrict__ A_log,
                                                  const float* __restrict__ Dp,
                                                  const float* __restrict__ Hin,
                                                  float* __restrict__ g) {
  int wave = threadIdx.x >> 6;
  int lane = threadIdx.x & 63;
  int s = lane & 15;
  int c = lane >> 4;
  int chunk = blockIdx.x >> 8;
  int chg = blockIdx.x & 255;
  int ch = chg * 16 + wave * 4 + c;
  int bn = ch >> 10;
  int d = ch & (D_INNER - 1);

  float A = -__expf(A_log[d * D_STATE + s]);
  float Dpd = Dp[d];
  int m0 = (bn << 10) + chunk * LC;

  float h = Hin[chunk * NCHS + ch * D_STATE + s];

  for (int l = 0; l < LC; ++l) {
    int m = m0 + l;
    float dtv = dt[(size_t)m * D_INNER + d];
    float uv = u[(size_t)m * D_INNER + d];
    float Bv = proj[m * 64 + 32 + s];
    float Cv = proj[m * 64 + 48 + s];
    float rv = xr[(size_t)m * 2048 + D_INNER + d];
    float a = __expf(dtv * A);
    h = fmaf(a, h, dtv * Bv * uv);
    float p = h * Cv;
    p += __shfl_xor(p, 1);
    p += __shfl_xor(p, 2);
    p += __shfl_xor(p, 4);
    p += __shfl_xor(p, 8);
    if (s == 0) {
      float yv = p + uv * Dpd;
      float sg = 1.f / (1.f + __expf(-rv));
      g[(size_t)m * D_INNER + d] = yv * (rv * sg);
    }
  }
}

extern "C" void kernel_launch(void* const* d_in, const int* in_sizes, int n_in,
                              void* d_out, int out_size, void* d_ws, size_t ws_size,
                              hipStream_t stream) {
  const float* x      = (const float*)d_in[0];   // (2,2,1024,512)
  const float* W_in   = (const float*)d_in[1];   // (2048, 512)
  const float* conv_w = (const float*)d_in[2];   // (2048, 4)
  const float* conv_b = (const float*)d_in[3];   // (2048,)
  const float* W_x    = (const float*)d_in[4];   // (64, 1024)
  const float* W_dt   = (const float*)d_in[5];   // (1024, 32)
  const float* b_dt   = (const float*)d_in[6];   // (1024,)
  const float* A_log  = (const float*)d_in[7];   // (1024, 16)
  const float* Dp     = (const float*)d_in[8];   // (1024,)
  const float* W_out  = (const float*)d_in[9];   // (512, 1024)
  float* out = (float*)d_out;                    // (2,2,1024,512)

  float* ws = (float*)d_ws;
  float* xr   = ws;                          // [4096][2048]  (x_in | res)
  float* u    = xr + (size_t)M_ROWS * 2048;  // [4096][1024]
  float* proj = u + (size_t)M_ROWS * 1024;   // [4096][64]
  float* dt   = proj + (size_t)M_ROWS * 64;  // [4096][1024]
  float* g    = dt + (size_t)M_ROWS * 1024;  // [4096][1024]
  float* Pbuf = g + (size_t)M_ROWS * 1024;   // [CH][65536]
  float* Sbuf = Pbuf + (size_t)CH * NCHS;    // [CH][65536]
  float* Hin  = Sbuf + (size_t)CH * NCHS;    // [CH][65536]

  // 1) in-proj GEMM: xr = x @ W_in^T   (M=4096, N=2048, K=512)
  {
    dim3 grid(2048 / BNT, M_ROWS / BM);
    gemm_f32<<<grid, 256, 0, stream>>>(x, W_in, xr, M_ROWS, 2048, DM_);
  }
  // 2) depthwise conv + SiLU -> u
  conv_silu_kernel<<<(M_ROWS * D_INNER) / 256, 256, 0, stream>>>(xr, conv_w, conv_b, u);
  // 3) x-proj -> proj (dt_raw | B | C)
  proj_kernel<<<M_ROWS / 4, 256, 0, stream>>>(u, W_x, proj);
  // 4) dt-proj + softplus -> dt
  {
    dim3 grid(D_INNER / 256, M_ROWS);
    dt_kernel<<<grid, 256, 0, stream>>>(proj, W_dt, b_dt, dt);
  }
  // 5) chunked selective scan + gating -> g
  scan_passA<<<256 * CH, 256, 0, stream>>>(dt, u, proj, A_log, Pbuf, Sbuf);
  scan_passB<<<NCHS / 256, 256, 0, stream>>>(Pbuf, Sbuf, Hin);
  scan_passC<<<256 * CH, 256, 0, stream>>>(dt, u, proj, xr, A_log, Dp, Hin, g);
  // 6) out-proj GEMM: out = g @ W_out^T (M=4096, N=512, K=1024)
  {
    dim3 grid(512 / BNT, M_ROWS / BM);
    gemm_f32<<<grid, 256, 0, stream>>>(g, W_out, out, M_ROWS, 512, D_INNER);
  }
}

// Round 3
// 437.988 us; speedup vs baseline: 1.8350x; 1.2826x over previous
//
#include <hip/hip_runtime.h>
#include <hip/hip_bf16.h>
#include <math.h>

// Problem constants (B,N,L,DM) = (2,2,1024,512), EXPAND=2, D_STATE=16, D_CONV=4
// D_INNER = 1024, DT_RANK = 32, BN_ = B*N = 4, M = BN_*L = 4096
#define L_SEQ   1024
#define DM_     512
#define D_INNER 1024
#define D_STATE 16
#define DT_RANK 32
#define BN_     4
#define M_ROWS  4096

// chunked scan
#define CH   16            // chunks per sequence
#define LC   (L_SEQ / CH)  // 64 steps per chunk
#define NCHS (M_ROWS * D_STATE)  // 4096 channels * 16 states = 65536

// x-proj split-K
#define KSPLIT 4
#define KCH    (D_INNER / KSPLIT)  // 256

// ---------------- f32 tiled GEMM: C[M,N] = A[M,K] @ W[N,K]^T ----------------
#define BM 64
#define BNT 64
#define BK 16

__global__ __launch_bounds__(256) void gemm_f32(const float* __restrict__ A,
                                                const float* __restrict__ W,
                                                float* __restrict__ C,
                                                int Mdim, int Ndim, int Kdim) {
  __shared__ float As[BK][BM];
  __shared__ float Bs[BK][BNT];
  const int tid = threadIdx.x;
  const int bm = blockIdx.y * BM;
  const int bn = blockIdx.x * BNT;
  const int tx = tid & 15;       // 0..15 -> 4 cols each
  const int ty = tid >> 4;       // 0..15 -> 4 rows each
  const int lr = tid >> 2;       // 0..63 row within tile for loads
  const int lk = (tid & 3) * 4;  // k offset 0,4,8,12

  float acc[4][4] = {};

  for (int k0 = 0; k0 < Kdim; k0 += BK) {
    float4 av = *(const float4*)&A[(size_t)(bm + lr) * Kdim + k0 + lk];
    float4 bv = *(const float4*)&W[(size_t)(bn + lr) * Kdim + k0 + lk];
    __syncthreads();
    As[lk + 0][lr] = av.x; As[lk + 1][lr] = av.y;
    As[lk + 2][lr] = av.z; As[lk + 3][lr] = av.w;
    Bs[lk + 0][lr] = bv.x; Bs[lk + 1][lr] = bv.y;
    Bs[lk + 2][lr] = bv.z; Bs[lk + 3][lr] = bv.w;
    __syncthreads();
#pragma unroll
    for (int k = 0; k < BK; ++k) {
      float ar[4], br[4];
      *(float4*)ar = *(const float4*)&As[k][ty * 4];
      *(float4*)br = *(const float4*)&Bs[k][tx * 4];
#pragma unroll
      for (int i = 0; i < 4; ++i)
#pragma unroll
        for (int j = 0; j < 4; ++j)
          acc[i][j] = fmaf(ar[i], br[j], acc[i][j]);
    }
  }
#pragma unroll
  for (int i = 0; i < 4; ++i) {
    int row = bm + ty * 4 + i;
    float4 v = make_float4(acc[i][0], acc[i][1], acc[i][2], acc[i][3]);
    *(float4*)&C[(size_t)row * Ndim + bn + tx * 4] = v;
  }
}

// ---------------- depthwise causal conv (d_conv=4) + SiLU ----------------
// xr layout: [M_ROWS][2048]; cols 0..1023 = x_in, 1024..2047 = res
__global__ __launch_bounds__(256) void conv_silu_kernel(const float* __restrict__ xr,
                                                        const float* __restrict__ cw,
                                                        const float* __restrict__ cb,
                                                        float* __restrict__ u) {
  int idx = blockIdx.x * 256 + threadIdx.x;  // over M_ROWS * D_INNER
  int d = idx & (D_INNER - 1);
  int m = idx >> 10;
  int l = m & (L_SEQ - 1);
  int bn = m >> 10;
  int ch = (bn & 1) * D_INNER + d;  // n = bn % N, N=2
  float acc = cb[ch];
  const float* base = xr + (size_t)(bn << 10) * 2048 + d;
#pragma unroll
  for (int k = 0; k < 4; ++k) {
    int ll = l - 3 + k;
    if (ll >= 0) acc = fmaf(cw[ch * 4 + k], base[(size_t)ll * 2048], acc);
  }
  float sig = 1.f / (1.f + __expf(-acc));
  u[idx] = acc * sig;
}

// ---------------- x-proj split-K: partial[kc][M,64] = u[:,kc*256+...] @ Wx^T ----------------
__global__ __launch_bounds__(256) void proj_gemm(const float* __restrict__ u,
                                                 const float* __restrict__ Wx,
                                                 float* __restrict__ partial) {
  __shared__ float As[BK][BM];
  __shared__ float Bs[BK][BNT];
  const int tid = threadIdx.x;
  const int bm = blockIdx.x * BM;       // 64 m-tiles
  const int kc = blockIdx.y;            // 0..3 k-chunk
  const int tx = tid & 15;
  const int ty = tid >> 4;
  const int lr = tid >> 2;
  const int lk = (tid & 3) * 4;

  float acc[4][4] = {};

  for (int k0 = 0; k0 < KCH; k0 += BK) {
    int kk = kc * KCH + k0 + lk;
    float4 av = *(const float4*)&u[(size_t)(bm + lr) * D_INNER + kk];
    float4 bv = *(const float4*)&Wx[(size_t)lr * D_INNER + kk];
    __syncthreads();
    As[lk + 0][lr] = av.x; As[lk + 1][lr] = av.y;
    As[lk + 2][lr] = av.z; As[lk + 3][lr] = av.w;
    Bs[lk + 0][lr] = bv.x; Bs[lk + 1][lr] = bv.y;
    Bs[lk + 2][lr] = bv.z; Bs[lk + 3][lr] = bv.w;
    __syncthreads();
#pragma unroll
    for (int k = 0; k < BK; ++k) {
      float ar[4], br[4];
      *(float4*)ar = *(const float4*)&As[k][ty * 4];
      *(float4*)br = *(const float4*)&Bs[k][tx * 4];
#pragma unroll
      for (int i = 0; i < 4; ++i)
#pragma unroll
        for (int j = 0; j < 4; ++j)
          acc[i][j] = fmaf(ar[i], br[j], acc[i][j]);
    }
  }
#pragma unroll
  for (int i = 0; i < 4; ++i) {
    int row = bm + ty * 4 + i;
    float4 v = make_float4(acc[i][0], acc[i][1], acc[i][2], acc[i][3]);
    *(float4*)&partial[((size_t)kc * M_ROWS + row) * 64 + tx * 4] = v;
  }
}

// reduce 4 partials -> proj[M,64]
__global__ __launch_bounds__(256) void proj_reduce(const float* __restrict__ partial,
                                                   float* __restrict__ proj) {
  int idx = blockIdx.x * 256 + threadIdx.x;  // over M_ROWS*64
  float s = partial[idx] + partial[(size_t)M_ROWS * 64 + idx] +
            partial[2 * (size_t)M_ROWS * 64 + idx] + partial[3 * (size_t)M_ROWS * 64 + idx];
  proj[idx] = s;
}

// ---------------- dt-proj + softplus: dt[M,1024] ----------------
__global__ __launch_bounds__(256) void dt_kernel(const float* __restrict__ proj,
                                                 const float* __restrict__ Wdt,
                                                 const float* __restrict__ bdt,
                                                 float* __restrict__ dt) {
  __shared__ float row[DT_RANK];
  int m = blockIdx.y;
  int d = blockIdx.x * 256 + threadIdx.x;
  if (threadIdx.x < DT_RANK) row[threadIdx.x] = proj[m * 64 + threadIdx.x];
  __syncthreads();
  float acc = bdt[d];
  const float* w = Wdt + (size_t)d * DT_RANK;
#pragma unroll
  for (int r = 0; r < DT_RANK; r += 4) {
    float4 ww = *(const float4*)(w + r);
    acc = fmaf(row[r + 0], ww.x, acc);
    acc = fmaf(row[r + 1], ww.y, acc);
    acc = fmaf(row[r + 2], ww.z, acc);
    acc = fmaf(row[r + 3], ww.w, acc);
  }
  // stable softplus
  float sp = fmaxf(acc, 0.f) + log1pf(__expf(-fabsf(acc)));
  dt[(size_t)m * D_INNER + d] = sp;
}

// ---------------- chunked selective scan ----------------
// lane layout: lane = c*16 + s ; wave handles 4 channels; block = 16 channels
// blockIdx.x: low 8 bits = channel-group (256 groups of 16), high bits = chunk

// Pass A: per (ch, s, chunk) compute transfer P = prod(a), S = local scan from 0
__global__ __launch_bounds__(256) void scan_passA(const float* __restrict__ dt,
                                                  const float* __restrict__ u,
                                                  const float* __restrict__ proj,
                                                  const float* __restrict__ A_log,
                                                  float* __restrict__ Pbuf,
                                                  float* __restrict__ Sbuf) {
  int wave = threadIdx.x >> 6;
  int lane = threadIdx.x & 63;
  int s = lane & 15;
  int c = lane >> 4;
  int chunk = blockIdx.x >> 8;
  int chg = blockIdx.x & 255;
  int ch = chg * 16 + wave * 4 + c;  // 0..4095
  int bn = ch >> 10;
  int d = ch & (D_INNER - 1);

  float A = -__expf(A_log[d * D_STATE + s]);
  int m0 = (bn << 10) + chunk * LC;

  float P = 1.f, S = 0.f;
  for (int l = 0; l < LC; ++l) {
    int m = m0 + l;
    float dtv = dt[(size_t)m * D_INNER + d];
    float uv = u[(size_t)m * D_INNER + d];
    float Bv = proj[m * 64 + 32 + s];
    float a = __expf(dtv * A);
    float b = dtv * Bv * uv;
    P *= a;
    S = fmaf(a, S, b);
  }
  int gid = ch * D_STATE + s;
  Pbuf[chunk * NCHS + gid] = P;
  Sbuf[chunk * NCHS + gid] = S;
}

// Pass B: serial prefix over chunks -> h_in per chunk
__global__ __launch_bounds__(256) void scan_passB(const float* __restrict__ Pbuf,
                                                  const float* __restrict__ Sbuf,
                                                  float* __restrict__ Hin) {
  int gid = blockIdx.x * 256 + threadIdx.x;  // 0..NCHS-1
  float h = 0.f;
#pragma unroll
  for (int cidx = 0; cidx < CH; ++cidx) {
    Hin[cidx * NCHS + gid] = h;
    h = fmaf(Pbuf[cidx * NCHS + gid], h, Sbuf[cidx * NCHS + gid]);
  }
}

// Pass C: recompute chunk scan from h_in, reduce over s, gate, write g
__global__ __launch_bounds__(256) void scan_passC(const float* __restrict__ dt,
                                                  const float* __restrict__ u,
                                                  const float* __restrict__ proj,
                                                  const float* __restrict__ xr,
                                                  const float* __restrict__ A_log,
                                                  const float* __restrict__ Dp,
                                                  const float* __restrict__ Hin,
                                                  float* __restrict__ g) {
  int wave = threadIdx.x >> 6;
  int lane = threadIdx.x & 63;
  int s = lane & 15;
  int c = lane >> 4;
  int chunk = blockIdx.x >> 8;
  int chg = blockIdx.x & 255;
  int ch = chg * 16 + wave * 4 + c;
  int bn = ch >> 10;
  int d = ch & (D_INNER - 1);

  float A = -__expf(A_log[d * D_STATE + s]);
  float Dpd = Dp[d];
  int m0 = (bn << 10) + chunk * LC;

  float h = Hin[chunk * NCHS + ch * D_STATE + s];

  for (int l = 0; l < LC; ++l) {
    int m = m0 + l;
    float dtv = dt[(size_t)m * D_INNER + d];
    float uv = u[(size_t)m * D_INNER + d];
    float Bv = proj[m * 64 + 32 + s];
    float Cv = proj[m * 64 + 48 + s];
    float rv = xr[(size_t)m * 2048 + D_INNER + d];
    float a = __expf(dtv * A);
    h = fmaf(a, h, dtv * Bv * uv);
    float p = h * Cv;
    p += __shfl_xor(p, 1);
    p += __shfl_xor(p, 2);
    p += __shfl_xor(p, 4);
    p += __shfl_xor(p, 8);
    if (s == 0) {
      float yv = p + uv * Dpd;
      float sg = 1.f / (1.f + __expf(-rv));
      g[(size_t)m * D_INNER + d] = yv * (rv * sg);
    }
  }
}

extern "C" void kernel_launch(void* const* d_in, const int* in_sizes, int n_in,
                              void* d_out, int out_size, void* d_ws, size_t ws_size,
                              hipStream_t stream) {
  const float* x      = (const float*)d_in[0];   // (2,2,1024,512)
  const float* W_in   = (const float*)d_in[1];   // (2048, 512)
  const float* conv_w = (const float*)d_in[2];   // (2048, 4)
  const float* conv_b = (const float*)d_in[3];   // (2048,)
  const float* W_x    = (const float*)d_in[4];   // (64, 1024)
  const float* W_dt   = (const float*)d_in[5];   // (1024, 32)
  const float* b_dt   = (const float*)d_in[6];   // (1024,)
  const float* A_log  = (const float*)d_in[7];   // (1024, 16)
  const float* Dp     = (const float*)d_in[8];   // (1024,)
  const float* W_out  = (const float*)d_in[9];   // (512, 1024)
  float* out = (float*)d_out;                    // (2,2,1024,512)

  float* ws = (float*)d_ws;
  float* xr   = ws;                          // [4096][2048]  (x_in | res)
  float* u    = xr + (size_t)M_ROWS * 2048;  // [4096][1024]
  float* proj = u + (size_t)M_ROWS * 1024;   // [4096][64]
  float* dt   = proj + (size_t)M_ROWS * 64;  // [4096][1024]
  float* g    = dt + (size_t)M_ROWS * 1024;  // [4096][1024]
  float* Pbuf = g + (size_t)M_ROWS * 1024;   // [CH][65536]
  float* Sbuf = Pbuf + (size_t)CH * NCHS;    // [CH][65536]
  float* Hin  = Sbuf + (size_t)CH * NCHS;    // [CH][65536]
  float* partial = Hin + (size_t)CH * NCHS;  // [KSPLIT][4096][64]

  // 1) in-proj GEMM: xr = x @ W_in^T   (M=4096, N=2048, K=512)
  {
    dim3 grid(2048 / BNT, M_ROWS / BM);
    gemm_f32<<<grid, 256, 0, stream>>>(x, W_in, xr, M_ROWS, 2048, DM_);
  }
  // 2) depthwise conv + SiLU -> u
  conv_silu_kernel<<<(M_ROWS * D_INNER) / 256, 256, 0, stream>>>(xr, conv_w, conv_b, u);
  // 3) x-proj (split-K GEMM + reduce) -> proj (dt_raw | B | C)
  {
    dim3 grid(M_ROWS / BM, KSPLIT);
    proj_gemm<<<grid, 256, 0, stream>>>(u, W_x, partial);
    proj_reduce<<<(M_ROWS * 64) / 256, 256, 0, stream>>>(partial, proj);
  }
  // 4) dt-proj + softplus -> dt
  {
    dim3 grid(D_INNER / 256, M_ROWS);
    dt_kernel<<<grid, 256, 0, stream>>>(proj, W_dt, b_dt, dt);
  }
  // 5) chunked selective scan + gating -> g
  scan_passA<<<256 * CH, 256, 0, stream>>>(dt, u, proj, A_log, Pbuf, Sbuf);
  scan_passB<<<NCHS / 256, 256, 0, stream>>>(Pbuf, Sbuf, Hin);
  scan_passC<<<256 * CH, 256, 0, stream>>>(dt, u, proj, xr, A_log, Dp, Hin, g);
  // 6) out-proj GEMM: out = g @ W_out^T (M=4096, N=512, K=1024)
  {
    dim3 grid(512 / BNT, M_ROWS / BM);
    gemm_f32<<<grid, 256, 0, stream>>>(g, W_out, out, M_ROWS, 512, D_INNER);
  }
}